// Round 25
// baseline (274.358 us; speedup 1.0000x reference)
//
#include <hip/hip_runtime.h>
#include <math.h>

typedef _Float16 f16;
typedef _Float16 f16x8 __attribute__((ext_vector_type(8)));
typedef _Float16 f16x4 __attribute__((ext_vector_type(4)));
typedef float f32x4 __attribute__((ext_vector_type(4)));

#define ROWS 88            // si row-dim stride (f16); rows 0..79 used
#define NTHREADS 256

__device__ __forceinline__ float ssim_px(float m1, float m2, float mss, float m12) {
  const float C1 = 0.0001f, C2 = 0.0009f;
  const float mu1s = m1 * m1, mu2s = m2 * m2, mu12 = m1 * m2;
  const float num = (2.f * mu12 + C1) * (2.f * (m12 - mu12) + C2);
  const float den = (mu1s + mu2s + C1) * (mss - mu1s - mu2s + C2);
  return num * __builtin_amdgcn_rcpf(den);
}

__device__ __forceinline__ unsigned pk2(float a, float b) {
  return __builtin_bit_cast(unsigned, __builtin_amdgcn_cvt_pkrtz(a, b));
}
__device__ __forceinline__ f16x4 pk4(const f32x4& d) {
  union { unsigned u[2]; f16x4 v; } r;
  r.u[0] = pk2(d[0], d[1]);
  r.u[1] = pk2(d[2], d[3]);
  return r.v;
}

// ---- 2-deep rolling h pipeline: issue group RG into slot S ----
#define H_ISSUE(RG, S)                                                         \
  {                                                                            \
    const int rimg = gy0 + (RG) * 16 + n;                                      \
    size_t base;                                                               \
    if (MASKED) {                                                              \
      const bool octok = (xb >= 0) && (xb <= 504);                             \
      const bool rok = (rimg >= 0) && (rimg < 512);                            \
      ok[S] = (rok && octok) ? 1.f : 0.f;                                      \
      base = ((size_t)(rok ? rimg : 0) << 9) + (size_t)(octok ? xb : 0);       \
    } else {                                                                   \
      ok[S] = 1.f;                                                             \
      base = ((size_t)rimg << 9) + (size_t)xb;                                 \
    }                                                                          \
    A0[S] = *(const float4*)(p1 + base);                                       \
    A1[S] = *(const float4*)(p1 + base + 4);                                   \
    B0[S] = *(const float4*)(p2 + base);                                       \
    B1[S] = *(const float4*)(p2 + base + 4);                                   \
  }

// ---- consume slot S (group RG): packed cvt + pk products + 4 MFMA + write --
#define H_CONSUME(RG, S)                                                       \
  {                                                                            \
    float4 a0 = A0[S], a1 = A1[S], b0 = B0[S], b1 = B1[S];                     \
    if (MASKED) {                                                              \
      const float m = ok[S];                                                   \
      a0.x *= m; a0.y *= m; a0.z *= m; a0.w *= m;                              \
      a1.x *= m; a1.y *= m; a1.z *= m; a1.w *= m;                              \
      b0.x *= m; b0.y *= m; b0.z *= m; b0.w *= m;                              \
      b1.x *= m; b1.y *= m; b1.z *= m; b1.w *= m;                              \
    }                                                                          \
    union { f16x8 v; unsigned u[4]; } ua, ub;                                  \
    ua.u[0] = pk2(a0.x, a0.y); ua.u[1] = pk2(a0.z, a0.w);                      \
    ua.u[2] = pk2(a1.x, a1.y); ua.u[3] = pk2(a1.z, a1.w);                      \
    ub.u[0] = pk2(b0.x, b0.y); ub.u[1] = pk2(b0.z, b0.w);                      \
    ub.u[2] = pk2(b1.x, b1.y); ub.u[3] = pk2(b1.z, b1.w);                      \
    const f16x8 fa = ua.v, fb = ub.v;                                          \
    const f16x8 fp = fa * fb;              /* v_pk_mul_f16 */                  \
    const f16x8 fs = fa * fa + fb * fb;    /* v_pk_mul + v_pk_fma */           \
    const f32x4 z = {0.f, 0.f, 0.f, 0.f};                                      \
    const f32x4 Da = __builtin_amdgcn_mfma_f32_16x16x32_f16(fa, Bh, z, 0, 0, 0); \
    const f32x4 Db = __builtin_amdgcn_mfma_f32_16x16x32_f16(fb, Bh, z, 0, 0, 0); \
    const f32x4 Ds = __builtin_amdgcn_mfma_f32_16x16x32_f16(fs, Bh, z, 0, 0, 0); \
    const f32x4 Dp = __builtin_amdgcn_mfma_f32_16x16x32_f16(fp, Bh, z, 0, 0, 0); \
    const int sr = (RG) * 16 + kg * 4;                                         \
    *(f16x4*)&si[0][px][sr] = pk4(Da);                                         \
    *(f16x4*)&si[1][px][sr] = pk4(Db);                                         \
    *(f16x4*)&si[2][px][sr] = pk4(Ds);                                         \
    *(f16x4*)&si[3][px][sr] = pk4(Dp);                                         \
  }

// H phase: pinned 2-deep rolling pipeline (counted vmcnt by construction).
template <bool MASKED>
__device__ __forceinline__ void h_phase(
    const float* __restrict__ p1, const float* __restrict__ p2,
    f16 (*si)[64][ROWS],
    int gy0, int xb, int px, int n, int kg, const f16x8& Bh)
{
  float4 A0[2], A1[2], B0[2], B1[2];   // static indices after expansion
  float ok[2];
  H_ISSUE(0, 0)
  H_ISSUE(1, 1)
  __builtin_amdgcn_sched_barrier(0);
  H_CONSUME(0, 0)
  H_ISSUE(2, 0)
  __builtin_amdgcn_sched_barrier(0);
  H_CONSUME(1, 1)
  H_ISSUE(3, 1)
  __builtin_amdgcn_sched_barrier(0);
  H_CONSUME(2, 0)
  H_ISSUE(4, 0)
  __builtin_amdgcn_sched_barrier(0);
  H_CONSUME(3, 1)
  H_CONSUME(4, 0)
}

__global__ __launch_bounds__(NTHREADS) void ssim_main_kernel(
    const float* __restrict__ img1, const float* __restrict__ img2,
    unsigned* __restrict__ counter, float* __restrict__ partials,
    float* __restrict__ out, float norm, float cexp, double invN, int nBlocks)
{
  // transposed h-blur fields: si[field][px(64)][row(88)], f16. 45,056 B.
  // Columns [16*wv,16*wv+16) are PRIVATE to wave wv -> barrier-free pipeline
  // (same-wave DS ordering; verified R20 absmax 0).
  __shared__ f16 si[4][64][ROWS];
  __shared__ float sred[4];
  __shared__ bool lastBlock;

  const int tid = threadIdx.x;
  const int wv = tid >> 6, lane = tid & 63;
  const int n = lane & 15, kg = lane >> 4;

  int b = blockIdx.x;
  const int tx = b & 7; b >>= 3;
  const int ty = b & 7; b >>= 3;
  const float* __restrict__ p1 = img1 + (size_t)b * 262144;
  const float* __restrict__ p2 = img2 + (size_t)b * 262144;

  // ---- constant tap fragments ----
  // h: B[k][n] = g[k-n-3]; v: A[o][kr] = g[kr-o]; k = 8*kg+i
  f16x8 Bh, Av;
#pragma unroll
  for (int i = 0; i < 8; i++) {
    const int k = 8 * kg + i;
    {
      const int idx = k - n - 3;
      const float d = (float)(idx - 5);
      const float val = norm * exp2f(cexp * d * d);
      Bh[i] = (idx >= 0 && idx <= 10) ? (f16)val : (f16)0.f;
    }
    {
      const int idx = k - n;
      const float d = (float)(idx - 5);
      const float val = norm * exp2f(cexp * d * d);
      Av[i] = (idx >= 0 && idx <= 10) ? (f16)val : (f16)0.f;
    }
  }

  // ---- geometry ----
  const int X0 = tx * 64 + wv * 16;      // this wave's out-x base
  const int xb = X0 - 8 + 8 * kg;        // this lane's sample-octet base
  const int gy0 = ty * 64 - 5;
  const int px = wv * 16 + n;            // this lane's si column

  // ================= H phase (barrier-free, pipelined) =================
  const bool interior = (tx >= 1) && (tx <= 6) && (ty >= 1) && (ty <= 6);
  if (interior)
    h_phase<false>(p1, p2, si, gy0, xb, px, n, kg, Bh);
  else
    h_phase<true>(p1, p2, si, gy0, xb, px, n, kg, Bh);

  // ================= V phase: 4 output-row groups of 16 =================
  float acc4[4] = {0.f, 0.f, 0.f, 0.f};
#pragma unroll
  for (int og = 0; og < 4; og++) {
    const int srb = og * 16 + 8 * kg;    // B k-slice rows (contiguous 8)
    const f16x8 Ba = *(const f16x8*)&si[0][px][srb];
    const f16x8 Bb = *(const f16x8*)&si[1][px][srb];
    const f16x8 Bs = *(const f16x8*)&si[2][px][srb];
    const f16x8 Bp = *(const f16x8*)&si[3][px][srb];
    const f32x4 z = {0.f, 0.f, 0.f, 0.f};
    const f32x4 Ma = __builtin_amdgcn_mfma_f32_16x16x32_f16(Av, Ba, z, 0, 0, 0);
    const f32x4 Mb = __builtin_amdgcn_mfma_f32_16x16x32_f16(Av, Bb, z, 0, 0, 0);
    const f32x4 Ms = __builtin_amdgcn_mfma_f32_16x16x32_f16(Av, Bs, z, 0, 0, 0);
    const f32x4 Mp = __builtin_amdgcn_mfma_f32_16x16x32_f16(Av, Bp, z, 0, 0, 0);
#pragma unroll
    for (int r = 0; r < 4; r++)
      acc4[r] += ssim_px(Ma[r], Mb[r], Ms[r], Mp[r]);
  }
  float accSum = (acc4[0] + acc4[1]) + (acc4[2] + acc4[3]);

  // ---- block reduction + last-block finalize ----
  for (int off = 32; off > 0; off >>= 1)
    accSum += __shfl_down(accSum, off, 64);
  if (lane == 0) sred[wv] = accSum;
  __syncthreads();
  if (tid == 0) {
    partials[blockIdx.x] = sred[0] + sred[1] + sred[2] + sred[3];
    __threadfence();                       // release partial (device scope)
    const unsigned old = atomicAdd(counter, 1u);
    lastBlock = (old == (unsigned)nBlocks - 1u);
  }
  __syncthreads();

  if (lastBlock) {
    __threadfence();                       // acquire all partials
    double s = 0.0;
    for (int i = tid; i < nBlocks; i += NTHREADS) s += (double)partials[i];
    for (int off = 32; off > 0; off >>= 1)
      s += __shfl_down(s, off, 64);
    __shared__ double dred[4];
    if (lane == 0) dred[wv] = s;
    __syncthreads();
    if (tid == 0)
      out[0] = (float)(1.0 - (dred[0] + dred[1] + dred[2] + dred[3]) * invN);
  }
}

extern "C" void kernel_launch(void* const* d_in, const int* in_sizes, int n_in,
                              void* d_out, int out_size, void* d_ws, size_t ws_size,
                              hipStream_t stream) {
  const float* img1 = (const float*)d_in[0];
  const float* img2 = (const float*)d_in[1];
  float* out = (float*)d_out;
  unsigned* counter = (unsigned*)d_ws;
  float* partials = (float*)((char*)d_ws + 256);

  const int planes = in_sizes[0] / (512 * 512);   // 96
  const int nBlocks = planes * 8 * 8;             // 6144

  // taps: g(idx) = norm * exp2(cexp * (idx-5)^2), idx in [0,10]
  double sum = 0.0;
  for (int i = 0; i < 11; i++) {
    const double x = (double)(i - 5);
    sum += exp(-(x * x) / 4.5);
  }
  const float norm = (float)(1.0 / sum);
  const float cexp = (float)(-1.0 / (4.5 * 0.6931471805599453));

  const double invN = 1.0 / (double)in_sizes[0];

  hipMemsetAsync(d_ws, 0, 4, stream);   // zero the arrival counter (capturable)
  ssim_main_kernel<<<nBlocks, NTHREADS, 0, stream>>>(
      img1, img2, counter, partials, out, norm, cexp, invN, nBlocks);
}

// Round 26
// 68.362 us; speedup vs baseline: 4.0133x; 4.0133x over previous
//
#include <hip/hip_runtime.h>
#include <math.h>

typedef _Float16 f16;
typedef _Float16 f16x8 __attribute__((ext_vector_type(8)));
typedef _Float16 f16x4 __attribute__((ext_vector_type(4)));
typedef float f32x4 __attribute__((ext_vector_type(4)));

#define ROWS 88            // si row-dim stride (f16); rows 0..79 used
#define NTHREADS 256

__device__ __forceinline__ float ssim_px(float m1, float m2, float mss, float m12) {
  const float C1 = 0.0001f, C2 = 0.0009f;
  const float mu1s = m1 * m1, mu2s = m2 * m2, mu12 = m1 * m2;
  const float num = (2.f * mu12 + C1) * (2.f * (m12 - mu12) + C2);
  const float den = (mu1s + mu2s + C1) * (mss - mu1s - mu2s + C2);
  return num * __builtin_amdgcn_rcpf(den);
}

__device__ __forceinline__ unsigned pk2(float a, float b) {
  return __builtin_bit_cast(unsigned, __builtin_amdgcn_cvt_pkrtz(a, b));
}
__device__ __forceinline__ f16x4 pk4(const f32x4& d) {
  union { unsigned u[2]; f16x4 v; } r;
  r.u[0] = pk2(d[0], d[1]);
  r.u[1] = pk2(d[2], d[3]);
  return r.v;
}

// ---- 2-deep rolling h pipeline: issue group RG into slot S ----
#define H_ISSUE(RG, S)                                                         \
  {                                                                            \
    const int rimg = gy0 + (RG) * 16 + n;                                      \
    size_t base;                                                               \
    if (MASKED) {                                                              \
      const bool octok = (xb >= 0) && (xb <= 504);                             \
      const bool rok = (rimg >= 0) && (rimg < 512);                            \
      ok[S] = (rok && octok) ? 1.f : 0.f;                                      \
      base = ((size_t)(rok ? rimg : 0) << 9) + (size_t)(octok ? xb : 0);       \
    } else {                                                                   \
      ok[S] = 1.f;                                                             \
      base = ((size_t)rimg << 9) + (size_t)xb;                                 \
    }                                                                          \
    A0[S] = *(const float4*)(p1 + base);                                       \
    A1[S] = *(const float4*)(p1 + base + 4);                                   \
    B0[S] = *(const float4*)(p2 + base);                                       \
    B1[S] = *(const float4*)(p2 + base + 4);                                   \
  }

// ---- consume slot S (group RG): packed cvt + pk products + 4 MFMA + write --
#define H_CONSUME(RG, S)                                                       \
  {                                                                            \
    float4 a0 = A0[S], a1 = A1[S], b0 = B0[S], b1 = B1[S];                     \
    if (MASKED) {                                                              \
      const float m = ok[S];                                                   \
      a0.x *= m; a0.y *= m; a0.z *= m; a0.w *= m;                              \
      a1.x *= m; a1.y *= m; a1.z *= m; a1.w *= m;                              \
      b0.x *= m; b0.y *= m; b0.z *= m; b0.w *= m;                              \
      b1.x *= m; b1.y *= m; b1.z *= m; b1.w *= m;                              \
    }                                                                          \
    union { f16x8 v; unsigned u[4]; } ua, ub;                                  \
    ua.u[0] = pk2(a0.x, a0.y); ua.u[1] = pk2(a0.z, a0.w);                      \
    ua.u[2] = pk2(a1.x, a1.y); ua.u[3] = pk2(a1.z, a1.w);                      \
    ub.u[0] = pk2(b0.x, b0.y); ub.u[1] = pk2(b0.z, b0.w);                      \
    ub.u[2] = pk2(b1.x, b1.y); ub.u[3] = pk2(b1.z, b1.w);                      \
    const f16x8 fa = ua.v, fb = ub.v;                                          \
    const f16x8 fp = fa * fb;              /* v_pk_mul_f16 */                  \
    const f16x8 fs = fa * fa + fb * fb;    /* v_pk_mul + v_pk_fma */           \
    const f32x4 z = {0.f, 0.f, 0.f, 0.f};                                      \
    const f32x4 Da = __builtin_amdgcn_mfma_f32_16x16x32_f16(fa, Bh, z, 0, 0, 0); \
    const f32x4 Db = __builtin_amdgcn_mfma_f32_16x16x32_f16(fb, Bh, z, 0, 0, 0); \
    const f32x4 Ds = __builtin_amdgcn_mfma_f32_16x16x32_f16(fs, Bh, z, 0, 0, 0); \
    const f32x4 Dp = __builtin_amdgcn_mfma_f32_16x16x32_f16(fp, Bh, z, 0, 0, 0); \
    const int sr = (RG) * 16 + kg * 4;                                         \
    *(f16x4*)&si[0][px][sr] = pk4(Da);                                         \
    *(f16x4*)&si[1][px][sr] = pk4(Db);                                         \
    *(f16x4*)&si[2][px][sr] = pk4(Ds);                                         \
    *(f16x4*)&si[3][px][sr] = pk4(Dp);                                         \
  }

// H phase: pinned 2-deep rolling pipeline (counted vmcnt by construction).
template <bool MASKED>
__device__ __forceinline__ void h_phase(
    const float* __restrict__ p1, const float* __restrict__ p2,
    f16 (*si)[64][ROWS],
    int gy0, int xb, int px, int n, int kg, const f16x8& Bh)
{
  float4 A0[2], A1[2], B0[2], B1[2];   // static indices after expansion
  float ok[2];
  H_ISSUE(0, 0)
  H_ISSUE(1, 1)
  __builtin_amdgcn_sched_barrier(0);
  H_CONSUME(0, 0)
  H_ISSUE(2, 0)
  __builtin_amdgcn_sched_barrier(0);
  H_CONSUME(1, 1)
  H_ISSUE(3, 1)
  __builtin_amdgcn_sched_barrier(0);
  H_CONSUME(2, 0)
  H_ISSUE(4, 0)
  __builtin_amdgcn_sched_barrier(0);
  H_CONSUME(3, 1)
  H_CONSUME(4, 0)
}

__global__ __launch_bounds__(NTHREADS) void ssim_main_kernel(
    const float* __restrict__ img1, const float* __restrict__ img2,
    float* __restrict__ partials, float norm, float cexp)
{
  // transposed h-blur fields: si[field][px(64)][row(88)], f16. 45,056 B.
  // Columns [16*wv,16*wv+16) are PRIVATE to wave wv -> barrier-free pipeline
  // (same-wave DS ordering; verified R20/R24 absmax 0).
  __shared__ f16 si[4][64][ROWS];
  __shared__ float sred[4];

  const int tid = threadIdx.x;
  const int wv = tid >> 6, lane = tid & 63;
  const int n = lane & 15, kg = lane >> 4;

  int b = blockIdx.x;
  const int tx = b & 7; b >>= 3;
  const int ty = b & 7; b >>= 3;
  const float* __restrict__ p1 = img1 + (size_t)b * 262144;
  const float* __restrict__ p2 = img2 + (size_t)b * 262144;

  // ---- constant tap fragments ----
  // h: B[k][n] = g[k-n-3]; v: A[o][kr] = g[kr-o]; k = 8*kg+i
  f16x8 Bh, Av;
#pragma unroll
  for (int i = 0; i < 8; i++) {
    const int k = 8 * kg + i;
    {
      const int idx = k - n - 3;
      const float d = (float)(idx - 5);
      const float val = norm * exp2f(cexp * d * d);
      Bh[i] = (idx >= 0 && idx <= 10) ? (f16)val : (f16)0.f;
    }
    {
      const int idx = k - n;
      const float d = (float)(idx - 5);
      const float val = norm * exp2f(cexp * d * d);
      Av[i] = (idx >= 0 && idx <= 10) ? (f16)val : (f16)0.f;
    }
  }

  // ---- geometry ----
  const int X0 = tx * 64 + wv * 16;      // this wave's out-x base
  const int xb = X0 - 8 + 8 * kg;        // this lane's sample-octet base
  const int gy0 = ty * 64 - 5;
  const int px = wv * 16 + n;            // this lane's si column

  // ================= H phase (barrier-free, pipelined) =================
  const bool interior = (tx >= 1) && (tx <= 6) && (ty >= 1) && (ty <= 6);
  if (interior)
    h_phase<false>(p1, p2, si, gy0, xb, px, n, kg, Bh);
  else
    h_phase<true>(p1, p2, si, gy0, xb, px, n, kg, Bh);

  // ================= V phase: 4 output-row groups of 16 =================
  float acc4[4] = {0.f, 0.f, 0.f, 0.f};
#pragma unroll
  for (int og = 0; og < 4; og++) {
    const int srb = og * 16 + 8 * kg;    // B k-slice rows (contiguous 8)
    const f16x8 Ba = *(const f16x8*)&si[0][px][srb];
    const f16x8 Bb = *(const f16x8*)&si[1][px][srb];
    const f16x8 Bs = *(const f16x8*)&si[2][px][srb];
    const f16x8 Bp = *(const f16x8*)&si[3][px][srb];
    const f32x4 z = {0.f, 0.f, 0.f, 0.f};
    const f32x4 Ma = __builtin_amdgcn_mfma_f32_16x16x32_f16(Av, Ba, z, 0, 0, 0);
    const f32x4 Mb = __builtin_amdgcn_mfma_f32_16x16x32_f16(Av, Bb, z, 0, 0, 0);
    const f32x4 Ms = __builtin_amdgcn_mfma_f32_16x16x32_f16(Av, Bs, z, 0, 0, 0);
    const f32x4 Mp = __builtin_amdgcn_mfma_f32_16x16x32_f16(Av, Bp, z, 0, 0, 0);
    // D: col = x (lane&15), row = out-row og*16 + kg*4 + reg; all rows valid
#pragma unroll
    for (int r = 0; r < 4; r++)
      acc4[r] += ssim_px(Ma[r], Mb[r], Ms[r], Mp[r]);
  }
  float accSum = (acc4[0] + acc4[1]) + (acc4[2] + acc4[3]);

  // ---- block reduction (only barrier in the kernel) ----
  for (int off = 32; off > 0; off >>= 1)
    accSum += __shfl_down(accSum, off, 64);
  if (lane == 0) sred[wv] = accSum;
  __syncthreads();
  if (tid == 0)
    partials[blockIdx.x] = sred[0] + sred[1] + sred[2] + sred[3];
}

__global__ __launch_bounds__(1024) void ssim_final_kernel(
    const float* __restrict__ partials, float* __restrict__ out,
    int n4, double invN)
{
  __shared__ double sred[16];
  const int tid = threadIdx.x;
  double s = 0.0;
  for (int i = tid; i < n4; i += 1024) {
    const float4 v = ((const float4*)partials)[i];
    s += (double)v.x + (double)v.y + (double)v.z + (double)v.w;
  }
  for (int off = 32; off > 0; off >>= 1)
    s += __shfl_down(s, off, 64);
  if ((tid & 63) == 0) sred[tid >> 6] = s;
  __syncthreads();
  if (tid == 0) {
    double tot = 0.0;
#pragma unroll
    for (int i = 0; i < 16; i++) tot += sred[i];
    out[0] = (float)(1.0 - tot * invN);
  }
}

extern "C" void kernel_launch(void* const* d_in, const int* in_sizes, int n_in,
                              void* d_out, int out_size, void* d_ws, size_t ws_size,
                              hipStream_t stream) {
  const float* img1 = (const float*)d_in[0];
  const float* img2 = (const float*)d_in[1];
  float* out = (float*)d_out;
  float* partials = (float*)d_ws;

  const int planes = in_sizes[0] / (512 * 512);   // 96
  const int nBlocks = planes * 8 * 8;             // 6144

  // taps: g(idx) = norm * exp2(cexp * (idx-5)^2), idx in [0,10]
  double sum = 0.0;
  for (int i = 0; i < 11; i++) {
    const double x = (double)(i - 5);
    sum += exp(-(x * x) / 4.5);
  }
  const float norm = (float)(1.0 / sum);
  const float cexp = (float)(-1.0 / (4.5 * 0.6931471805599453));

  const double invN = 1.0 / (double)in_sizes[0];

  ssim_main_kernel<<<nBlocks, NTHREADS, 0, stream>>>(img1, img2, partials, norm, cexp);
  ssim_final_kernel<<<1, 1024, 0, stream>>>(partials, out, nBlocks / 4, invN);
}

// Round 27
// 67.820 us; speedup vs baseline: 4.0454x; 1.0080x over previous
//
#include <hip/hip_runtime.h>
#include <math.h>

typedef _Float16 f16;
typedef _Float16 f16x8 __attribute__((ext_vector_type(8)));
typedef _Float16 f16x4 __attribute__((ext_vector_type(4)));
typedef float f32x4 __attribute__((ext_vector_type(4)));

#define ROWS 80            // si row-dim stride (f16): rows 0..79 exact; 40 KB total
#define NTHREADS 256

__device__ __forceinline__ float ssim_px(float m1, float m2, float mss, float m12) {
  const float C1 = 0.0001f, C2 = 0.0009f;
  const float mu1s = m1 * m1, mu2s = m2 * m2, mu12 = m1 * m2;
  const float num = (2.f * mu12 + C1) * (2.f * (m12 - mu12) + C2);
  const float den = (mu1s + mu2s + C1) * (mss - mu1s - mu2s + C2);
  return num * __builtin_amdgcn_rcpf(den);
}

__device__ __forceinline__ unsigned pk2(float a, float b) {
  return __builtin_bit_cast(unsigned, __builtin_amdgcn_cvt_pkrtz(a, b));
}
__device__ __forceinline__ f16x4 pk4(const f32x4& d) {
  union { unsigned u[2]; f16x4 v; } r;
  r.u[0] = pk2(d[0], d[1]);
  r.u[1] = pk2(d[2], d[3]);
  return r.v;
}

// ---- 2-deep rolling h pipeline: issue group RG into slot S ----
#define H_ISSUE(RG, S)                                                         \
  {                                                                            \
    const int rimg = gy0 + (RG) * 16 + n;                                      \
    size_t base;                                                               \
    if (MASKED) {                                                              \
      const bool octok = (xb >= 0) && (xb <= 504);                             \
      const bool rok = (rimg >= 0) && (rimg < 512);                            \
      ok[S] = (rok && octok) ? 1.f : 0.f;                                      \
      base = ((size_t)(rok ? rimg : 0) << 9) + (size_t)(octok ? xb : 0);       \
    } else {                                                                   \
      ok[S] = 1.f;                                                             \
      base = ((size_t)rimg << 9) + (size_t)xb;                                 \
    }                                                                          \
    A0[S] = *(const float4*)(p1 + base);                                       \
    A1[S] = *(const float4*)(p1 + base + 4);                                   \
    B0[S] = *(const float4*)(p2 + base);                                       \
    B1[S] = *(const float4*)(p2 + base + 4);                                   \
  }

// ---- consume slot S (group RG): packed cvt + pk products + 4 MFMA + write --
#define H_CONSUME(RG, S)                                                       \
  {                                                                            \
    float4 a0 = A0[S], a1 = A1[S], b0 = B0[S], b1 = B1[S];                     \
    if (MASKED) {                                                              \
      const float m = ok[S];                                                   \
      a0.x *= m; a0.y *= m; a0.z *= m; a0.w *= m;                              \
      a1.x *= m; a1.y *= m; a1.z *= m; a1.w *= m;                              \
      b0.x *= m; b0.y *= m; b0.z *= m; b0.w *= m;                              \
      b1.x *= m; b1.y *= m; b1.z *= m; b1.w *= m;                              \
    }                                                                          \
    union { f16x8 v; unsigned u[4]; } ua, ub;                                  \
    ua.u[0] = pk2(a0.x, a0.y); ua.u[1] = pk2(a0.z, a0.w);                      \
    ua.u[2] = pk2(a1.x, a1.y); ua.u[3] = pk2(a1.z, a1.w);                      \
    ub.u[0] = pk2(b0.x, b0.y); ub.u[1] = pk2(b0.z, b0.w);                      \
    ub.u[2] = pk2(b1.x, b1.y); ub.u[3] = pk2(b1.z, b1.w);                      \
    const f16x8 fa = ua.v, fb = ub.v;                                          \
    const f16x8 fp = fa * fb;              /* v_pk_mul_f16 */                  \
    const f16x8 fs = fa * fa + fb * fb;    /* v_pk_mul + v_pk_fma */           \
    const f32x4 z = {0.f, 0.f, 0.f, 0.f};                                      \
    const f32x4 Da = __builtin_amdgcn_mfma_f32_16x16x32_f16(fa, Bh, z, 0, 0, 0); \
    const f32x4 Db = __builtin_amdgcn_mfma_f32_16x16x32_f16(fb, Bh, z, 0, 0, 0); \
    const f32x4 Ds = __builtin_amdgcn_mfma_f32_16x16x32_f16(fs, Bh, z, 0, 0, 0); \
    const f32x4 Dp = __builtin_amdgcn_mfma_f32_16x16x32_f16(fp, Bh, z, 0, 0, 0); \
    const int sr = (RG) * 16 + kg * 4;                                         \
    *(f16x4*)&si[0][px][sr] = pk4(Da);                                         \
    *(f16x4*)&si[1][px][sr] = pk4(Db);                                         \
    *(f16x4*)&si[2][px][sr] = pk4(Ds);                                         \
    *(f16x4*)&si[3][px][sr] = pk4(Dp);                                         \
  }

// H phase: pinned 2-deep rolling pipeline (counted vmcnt by construction).
template <bool MASKED>
__device__ __forceinline__ void h_phase(
    const float* __restrict__ p1, const float* __restrict__ p2,
    f16 (*si)[64][ROWS],
    int gy0, int xb, int px, int n, int kg, const f16x8& Bh)
{
  float4 A0[2], A1[2], B0[2], B1[2];   // static indices after expansion
  float ok[2];
  H_ISSUE(0, 0)
  H_ISSUE(1, 1)
  __builtin_amdgcn_sched_barrier(0);
  H_CONSUME(0, 0)
  H_ISSUE(2, 0)
  __builtin_amdgcn_sched_barrier(0);
  H_CONSUME(1, 1)
  H_ISSUE(3, 1)
  __builtin_amdgcn_sched_barrier(0);
  H_CONSUME(2, 0)
  H_ISSUE(4, 0)
  __builtin_amdgcn_sched_barrier(0);
  H_CONSUME(3, 1)
  H_CONSUME(4, 0)
}

__global__ __launch_bounds__(NTHREADS) void ssim_main_kernel(
    const float* __restrict__ img1, const float* __restrict__ img2,
    float* __restrict__ partials, float norm, float cexp)
{
  // transposed h-blur fields: si[field][px(64)][row(80)], f16. 40,960 B
  // -> 4 blocks/CU potential. Columns [16*wv,16*wv+16) PRIVATE to wave wv ->
  // barrier-free pipeline (same-wave DS ordering; verified R20/R24 absmax 0).
  __shared__ f16 si[4][64][ROWS];
  __shared__ float sred[4];

  const int tid = threadIdx.x;
  const int wv = tid >> 6, lane = tid & 63;
  const int n = lane & 15, kg = lane >> 4;

  int b = blockIdx.x;
  const int tx = b & 7; b >>= 3;
  const int ty = b & 7; b >>= 3;
  const float* __restrict__ p1 = img1 + (size_t)b * 262144;
  const float* __restrict__ p2 = img2 + (size_t)b * 262144;

  // ---- constant tap fragments ----
  // h: B[k][n] = g[k-n-3]; v: A[o][kr] = g[kr-o]; k = 8*kg+i
  f16x8 Bh, Av;
#pragma unroll
  for (int i = 0; i < 8; i++) {
    const int k = 8 * kg + i;
    {
      const int idx = k - n - 3;
      const float d = (float)(idx - 5);
      const float val = norm * exp2f(cexp * d * d);
      Bh[i] = (idx >= 0 && idx <= 10) ? (f16)val : (f16)0.f;
    }
    {
      const int idx = k - n;
      const float d = (float)(idx - 5);
      const float val = norm * exp2f(cexp * d * d);
      Av[i] = (idx >= 0 && idx <= 10) ? (f16)val : (f16)0.f;
    }
  }

  // ---- geometry ----
  const int X0 = tx * 64 + wv * 16;      // this wave's out-x base
  const int xb = X0 - 8 + 8 * kg;        // this lane's sample-octet base
  const int gy0 = ty * 64 - 5;
  const int px = wv * 16 + n;            // this lane's si column

  // ================= H phase (barrier-free, pipelined) =================
  const bool interior = (tx >= 1) && (tx <= 6) && (ty >= 1) && (ty <= 6);
  if (interior)
    h_phase<false>(p1, p2, si, gy0, xb, px, n, kg, Bh);
  else
    h_phase<true>(p1, p2, si, gy0, xb, px, n, kg, Bh);

  // ================= V phase: 4 output-row groups of 16 =================
  float acc4[4] = {0.f, 0.f, 0.f, 0.f};
#pragma unroll
  for (int og = 0; og < 4; og++) {
    const int srb = og * 16 + 8 * kg;    // B k-slice rows (contiguous 8)
    const f16x8 Ba = *(const f16x8*)&si[0][px][srb];
    const f16x8 Bb = *(const f16x8*)&si[1][px][srb];
    const f16x8 Bs = *(const f16x8*)&si[2][px][srb];
    const f16x8 Bp = *(const f16x8*)&si[3][px][srb];
    const f32x4 z = {0.f, 0.f, 0.f, 0.f};
    const f32x4 Ma = __builtin_amdgcn_mfma_f32_16x16x32_f16(Av, Ba, z, 0, 0, 0);
    const f32x4 Mb = __builtin_amdgcn_mfma_f32_16x16x32_f16(Av, Bb, z, 0, 0, 0);
    const f32x4 Ms = __builtin_amdgcn_mfma_f32_16x16x32_f16(Av, Bs, z, 0, 0, 0);
    const f32x4 Mp = __builtin_amdgcn_mfma_f32_16x16x32_f16(Av, Bp, z, 0, 0, 0);
    // D: col = x (lane&15), row = out-row og*16 + kg*4 + reg; all rows valid
#pragma unroll
    for (int r = 0; r < 4; r++)
      acc4[r] += ssim_px(Ma[r], Mb[r], Ms[r], Mp[r]);
  }
  float accSum = (acc4[0] + acc4[1]) + (acc4[2] + acc4[3]);

  // ---- block reduction (only barrier in the kernel) ----
  for (int off = 32; off > 0; off >>= 1)
    accSum += __shfl_down(accSum, off, 64);
  if (lane == 0) sred[wv] = accSum;
  __syncthreads();
  if (tid == 0)
    partials[blockIdx.x] = sred[0] + sred[1] + sred[2] + sred[3];
}

__global__ __launch_bounds__(1024) void ssim_final_kernel(
    const float* __restrict__ partials, float* __restrict__ out,
    int n4, double invN)
{
  __shared__ double sred[16];
  const int tid = threadIdx.x;
  double s = 0.0;
  for (int i = tid; i < n4; i += 1024) {
    const float4 v = ((const float4*)partials)[i];
    s += (double)v.x + (double)v.y + (double)v.z + (double)v.w;
  }
  for (int off = 32; off > 0; off >>= 1)
    s += __shfl_down(s, off, 64);
  if ((tid & 63) == 0) sred[tid >> 6] = s;
  __syncthreads();
  if (tid == 0) {
    double tot = 0.0;
#pragma unroll
    for (int i = 0; i < 16; i++) tot += sred[i];
    out[0] = (float)(1.0 - tot * invN);
  }
}

extern "C" void kernel_launch(void* const* d_in, const int* in_sizes, int n_in,
                              void* d_out, int out_size, void* d_ws, size_t ws_size,
                              hipStream_t stream) {
  const float* img1 = (const float*)d_in[0];
  const float* img2 = (const float*)d_in[1];
  float* out = (float*)d_out;
  float* partials = (float*)d_ws;

  const int planes = in_sizes[0] / (512 * 512);   // 96
  const int nBlocks = planes * 8 * 8;             // 6144

  // taps: g(idx) = norm * exp2(cexp * (idx-5)^2), idx in [0,10]
  double sum = 0.0;
  for (int i = 0; i < 11; i++) {
    const double x = (double)(i - 5);
    sum += exp(-(x * x) / 4.5);
  }
  const float norm = (float)(1.0 / sum);
  const float cexp = (float)(-1.0 / (4.5 * 0.6931471805599453));

  const double invN = 1.0 / (double)in_sizes[0];

  ssim_main_kernel<<<nBlocks, NTHREADS, 0, stream>>>(img1, img2, partials, norm, cexp);
  ssim_final_kernel<<<1, 1024, 0, stream>>>(partials, out, nBlocks / 4, invN);
}